// Round 4
// baseline (529.988 us; speedup 1.0000x reference)
//
#include <hip/hip_runtime.h>

#define DEVI __device__ __forceinline__

typedef __bf16 bf16x8 __attribute__((ext_vector_type(8)));
typedef float f32x4 __attribute__((ext_vector_type(4)));

// ---------- exact bf16 RNE helpers ----------
DEVI unsigned short f2bf(float f) {
  unsigned u = __float_as_uint(f);
  u = (u + 0x7FFFu + ((u >> 16) & 1u)) >> 16;
  return (unsigned short)u;
}
DEVI float bf2f(unsigned short h) { return __uint_as_float(((unsigned)h) << 16); }
DEVI float bf16r(float f) { return bf2f(f2bf(f)); }

// ---------- fast MXINT8 scale from block amax (amax normal, >0) ----------
// shared_exp = floor(log2(amax)) = exponent field - 127 (bit extract, no libm).
// scale = 2^(se-6), inv = 2^(6-se), built by exponent-field arithmetic.
DEVI void mx_scales(float amax, float& scale, float& inv) {
  unsigned eb = __float_as_uint(amax) & 0x7f800000u;
  scale = __uint_as_float(eb - (6u << 23));          // 2^(e-6)
  inv   = __uint_as_float((260u << 23) - eb);        // 2^(6-e)  [(127+6-e)+127]<<23
}

// quantize one value given block amax; result exact in bf16 (<=8 sig bits)
DEVI unsigned short quantv(float v, float scale, float inv) {
  float qv = rintf(v * inv);                          // RNE, matches jnp.round
  qv = fminf(fmaxf(qv, -128.f), 127.f);
  return f2bf(qv * scale);
}

// ---------- MXINT8 fake-quant of 8 elements, given block amax ----------
DEVI void quant8(const float* h, float amax, unsigned short* q) {
  if (amax > 0.f) {
    float scale, inv;
    mx_scales(amax, scale, inv);
#pragma unroll
    for (int k = 0; k < 8; ++k) q[k] = quantv(h[k], scale, inv);
  } else {
#pragma unroll
    for (int k = 0; k < 8; ++k) q[k] = 0;
  }
}

// ---------- async global->LDS 16B ----------
DEVI void gl2lds16(const void* g, void* l) {
  __builtin_amdgcn_global_load_lds(
      (__attribute__((address_space(1))) void*)const_cast<void*>(g),
      (__attribute__((address_space(3))) void*)l, 16, 0, 0);
}

// ---------- weight quant: fp32 [.., K] -> MX bf16, blocks of 32 along flat ----------
__global__ __launch_bounds__(256) void quant_f32_k(const float* __restrict__ X,
                                                   unsigned short* __restrict__ Q) {
  size_t idx = (size_t)blockIdx.x * 256 + threadIdx.x;   // 8 elements per thread
  float4 v0 = ((const float4*)X)[idx * 2];
  float4 v1 = ((const float4*)X)[idx * 2 + 1];
  float h[8] = {v0.x, v0.y, v0.z, v0.w, v1.x, v1.y, v1.z, v1.w};
  float amax = 0.f;
#pragma unroll
  for (int k = 0; k < 8; ++k) amax = fmaxf(amax, fabsf(h[k]));
  amax = fmaxf(amax, __shfl_xor(amax, 1));   // 4 consecutive lanes = one 32-block
  amax = fmaxf(amax, __shfl_xor(amax, 2));
  unsigned short q[8];
  quant8(h, amax, q);
  uint4 o;
  o.x = (unsigned)q[0] | ((unsigned)q[1] << 16);
  o.y = (unsigned)q[2] | ((unsigned)q[3] << 16);
  o.z = (unsigned)q[4] | ((unsigned)q[5] << 16);
  o.w = (unsigned)q[6] | ((unsigned)q[7] << 16);
  ((uint4*)Q)[idx] = o;
}

// ---------- LayerNorm (on bf16-rounded input) + bf16 round + MX quant ----------
__global__ __launch_bounds__(256) void ln_quant_k(const float* __restrict__ X,
                                                  const float* __restrict__ w,
                                                  const float* __restrict__ b,
                                                  unsigned short* __restrict__ out) {
  const int H = 2048;
  const int row = blockIdx.x;
  const int t = threadIdx.x;
  const int lane = t & 63, wave = t >> 6;
  const float* xr = X + (size_t)row * H;
  float4 v0 = ((const float4*)xr)[2 * t];
  float4 v1 = ((const float4*)xr)[2 * t + 1];
  float x[8] = {bf16r(v0.x), bf16r(v0.y), bf16r(v0.z), bf16r(v0.w),
                bf16r(v1.x), bf16r(v1.y), bf16r(v1.z), bf16r(v1.w)};
  __shared__ float red[4];
  float s = 0.f;
#pragma unroll
  for (int k = 0; k < 8; ++k) s += x[k];
#pragma unroll
  for (int o = 32; o; o >>= 1) s += __shfl_xor(s, o);
  if (lane == 0) red[wave] = s;
  __syncthreads();
  float mu = (red[0] + red[1] + red[2] + red[3]) * (1.0f / H);
  __syncthreads();
  float v = 0.f;
#pragma unroll
  for (int k = 0; k < 8; ++k) { float d = x[k] - mu; v += d * d; }
#pragma unroll
  for (int o = 32; o; o >>= 1) v += __shfl_xor(v, o);
  if (lane == 0) red[wave] = v;
  __syncthreads();
  float var = (red[0] + red[1] + red[2] + red[3]) * (1.0f / H);
  float rstd = 1.0f / sqrtf(var + 1e-5f);
  float h[8];
  float amax = 0.f;
#pragma unroll
  for (int k = 0; k < 8; ++k) {
    int col = t * 8 + k;
    h[k] = bf16r((x[k] - mu) * rstd * w[col] + b[col]);
    amax = fmaxf(amax, fabsf(h[k]));
  }
  amax = fmaxf(amax, __shfl_xor(amax, 1));
  amax = fmaxf(amax, __shfl_xor(amax, 2));
  unsigned short q[8];
  quant8(h, amax, q);
  uint4 o4;
  o4.x = (unsigned)q[0] | ((unsigned)q[1] << 16);
  o4.y = (unsigned)q[2] | ((unsigned)q[3] << 16);
  o4.z = (unsigned)q[4] | ((unsigned)q[5] << 16);
  o4.w = (unsigned)q[6] | ((unsigned)q[7] << 16);
  ((uint4*)(out + (size_t)row * H))[t] = o4;
}

// ---------- GEMM: C[m,n] = sum_k A[m,k]*B[n,k], A/B bf16, fp32 acc ----------
// 128x128 tile, BK=64, 4 waves, each wave 64x64 (4x4 of 16x16x32 MFMA).
// LDS layout XOR-swizzled: 16B chunk c of row r lives at LDS chunk c^(r&7)
// (fixed 16-way ds_read conflicts: 5.03e7 -> 0, R3).
// MODE 1: h = bf16(gelu(bf16(y+bias))) then FUSED MX-quant along N (blocks of
//   32 cols; each block lives in one quad: 2 j-tiles x 16 lanes) -> bf16 [M,N]
// MODE 2: out = bf16(bf16(resid) + bf16(y + bias)) -> float [M,N]
template <int MODE>
__global__ __launch_bounds__(256) void gemm_mx(const unsigned short* __restrict__ A,
                                               const unsigned short* __restrict__ B,
                                               int M, int N, int K,
                                               const float* __restrict__ bias,
                                               const float* __restrict__ resid,
                                               void* __restrict__ outp) {
  __shared__ unsigned short As[128 * 64];
  __shared__ unsigned short Bs[128 * 64];

  const int tid = threadIdx.x;
  const int lane = tid & 63;
  const int wave = tid >> 6;
  const int wr = (wave >> 1) * 64;   // wave row offset in tile
  const int wc = (wave & 1) * 64;    // wave col offset in tile
  const int lr = lane & 15;
  const int quad = lane >> 4;

  const int m0 = blockIdx.y * 128;
  const int n0 = blockIdx.x * 128;

  // staging: 16KB per tile = 1024 x 16B units; LDS unit n (fixed dest n*16 B)
  // = row n>>3, LDS chunk n&7. Source global chunk = (n&7) ^ (row&7)  [swizzle].
  size_t aoff[4], boff[4];
  int lbase[4];
#pragma unroll
  for (int j = 0; j < 4; ++j) {
    int n = j * 256 + tid;
    int r = n >> 3, c = (n & 7) ^ (r & 7);
    aoff[j] = (size_t)(m0 + r) * K + (size_t)c * 8;
    boff[j] = (size_t)(n0 + r) * K + (size_t)c * 8;
    lbase[j] = (j * 256 + (tid & ~63)) * 8;  // wave-uniform LDS base (ushort units)
  }

  f32x4 acc[4][4];
#pragma unroll
  for (int i = 0; i < 4; ++i)
#pragma unroll
    for (int j = 0; j < 4; ++j) acc[i][j] = (f32x4){0.f, 0.f, 0.f, 0.f};

  for (int k0 = 0; k0 < K; k0 += 64) {
#pragma unroll
    for (int j = 0; j < 4; ++j) gl2lds16(A + aoff[j] + k0, As + lbase[j]);
#pragma unroll
    for (int j = 0; j < 4; ++j) gl2lds16(B + boff[j] + k0, Bs + lbase[j]);
    __syncthreads();  // drains vmcnt -> LDS tiles visible
#pragma unroll
    for (int s = 0; s < 2; ++s) {
      bf16x8 af[4], bfr[4];
#pragma unroll
      for (int i = 0; i < 4; ++i) {
        int row = wr + i * 16 + lr;
        int ch = (s * 4 + quad) ^ (row & 7);
        af[i] = *(const bf16x8*)(As + row * 64 + ch * 8);
      }
#pragma unroll
      for (int j = 0; j < 4; ++j) {
        int row = wc + j * 16 + lr;
        int ch = (s * 4 + quad) ^ (row & 7);
        bfr[j] = *(const bf16x8*)(Bs + row * 64 + ch * 8);
      }
#pragma unroll
      for (int i = 0; i < 4; ++i)
#pragma unroll
        for (int j = 0; j < 4; ++j)
          acc[i][j] = __builtin_amdgcn_mfma_f32_16x16x32_bf16(af[i], bfr[j], acc[i][j], 0, 0, 0);
    }
    __syncthreads();  // all reads done before next stage overwrites
  }

  // epilogue: D mapping col = lane&15, row = quad*4 + reg   [m89-verified]
  if (MODE == 1) {
#pragma unroll
    for (int i = 0; i < 4; ++i) {
#pragma unroll
      for (int r = 0; r < 4; ++r) {
        const int gm = m0 + wr + i * 16 + quad * 4 + r;
        float g[4];
#pragma unroll
        for (int j = 0; j < 4; ++j) {
          float t = bf16r(acc[i][j][r] + bias[n0 + wc + j * 16 + lr]);
          // tanh(u) = 1 - 2/(exp(2u)+1); exp via v_exp_f32 (fast, NaN-free here)
          float u2 = 1.5957691216057308f * (t + 0.044715f * t * t * t);  // 2*c*(...)
          float E = __expf(u2);
          float th = 1.0f - 2.0f / (E + 1.0f);
          g[j] = bf16r(0.5f * t * (1.0f + th));
        }
        // fused MX quant: block = 32 consecutive cols = {j0,j1} / {j2,j3}
        // across this quad's 16 lanes
        float a = fmaxf(fabsf(g[0]), fabsf(g[1]));
        float b = fmaxf(fabsf(g[2]), fabsf(g[3]));
#pragma unroll
        for (int mset = 1; mset < 16; mset <<= 1) {
          a = fmaxf(a, __shfl_xor(a, mset));
          b = fmaxf(b, __shfl_xor(b, mset));
        }
        unsigned short q[4];
        if (a > 0.f) {
          float sc, iv; mx_scales(a, sc, iv);
          q[0] = quantv(g[0], sc, iv); q[1] = quantv(g[1], sc, iv);
        } else { q[0] = q[1] = 0; }
        if (b > 0.f) {
          float sc, iv; mx_scales(b, sc, iv);
          q[2] = quantv(g[2], sc, iv); q[3] = quantv(g[3], sc, iv);
        } else { q[2] = q[3] = 0; }
        unsigned short* orow = (unsigned short*)outp + (size_t)gm * N + n0 + wc + lr;
#pragma unroll
        for (int j = 0; j < 4; ++j) orow[j * 16] = q[j];
      }
    }
  } else {
#pragma unroll
    for (int i = 0; i < 4; ++i) {
#pragma unroll
      for (int j = 0; j < 4; ++j) {
#pragma unroll
        for (int r = 0; r < 4; ++r) {
          int gm = m0 + wr + i * 16 + quad * 4 + r;
          int gn = n0 + wc + j * 16 + lr;
          float h = bf16r(acc[i][j][r] + bias[gn]);
          float rr = bf16r(resid[(size_t)gm * N + gn]);
          ((float*)outp)[(size_t)gm * N + gn] = bf16r(rr + h);
        }
      }
    }
  }
  (void)M;
}

extern "C" void kernel_launch(void* const* d_in, const int* in_sizes, int n_in,
                              void* d_out, int out_size, void* d_ws, size_t ws_size,
                              hipStream_t stream) {
  const float* inputs = (const float*)d_in[0];  // [2,2048,2048]
  const float* ln_w   = (const float*)d_in[1];  // [2048]
  const float* ln_b   = (const float*)d_in[2];  // [2048]
  const float* W1     = (const float*)d_in[3];  // [8192,2048]
  const float* b1     = (const float*)d_in[4];  // [8192]
  const float* W2     = (const float*)d_in[5];  // [2048,8192]
  const float* b2     = (const float*)d_in[6];  // [2048]
  float* out = (float*)d_out;                   // [2,2048,2048] fp32 (bf16-valued)
  char* ws = (char*)d_ws;
  (void)in_sizes; (void)n_in; (void)out_size; (void)ws_size;

  // workspace layout (144 MiB total)
  unsigned short* qW1  = (unsigned short*)(ws);                      // 32 MiB
  unsigned short* qW2  = (unsigned short*)(ws + (size_t)33554432);   // 32 MiB
  unsigned short* a1   = (unsigned short*)(ws + (size_t)67108864);   // 16 MiB [4096,2048]
  unsigned short* act2 = (unsigned short*)(ws + (size_t)83886080);   // 64 MiB [4096,8192]

  const int M = 4096;

  // 1-2. quantize weights to MX bf16
  quant_f32_k<<<8192, 256, 0, stream>>>(W1, qW1);
  quant_f32_k<<<8192, 256, 0, stream>>>(W2, qW2);

  // 3. bf16-round + LayerNorm + bf16-round + MX quant  (one block per row)
  ln_quant_k<<<M, 256, 0, stream>>>(inputs, ln_w, ln_b, a1);

  // 4. GEMM1 + bias + gelu + FUSED MX quant -> quantized bf16 [4096,8192]
  gemm_mx<1><<<dim3(8192 / 128, M / 128), 256, 0, stream>>>(
      a1, qW1, M, 8192, 2048, b1, nullptr, (void*)act2);

  // 5. GEMM2 [4096,8192] x [2048,8192]^T + bias + residual -> fp32 out
  gemm_mx<2><<<dim3(2048 / 128, M / 128), 256, 0, stream>>>(
      act2, qW2, M, 2048, 8192, b2, inputs, (void*)out);
}

// Round 5
// 523.702 us; speedup vs baseline: 1.0120x; 1.0120x over previous
//
#include <hip/hip_runtime.h>

#define DEVI __device__ __forceinline__

typedef __bf16 bf16x8 __attribute__((ext_vector_type(8)));
typedef float f32x4 __attribute__((ext_vector_type(4)));

// ---------- exact bf16 RNE helpers ----------
DEVI unsigned short f2bf(float f) {
  unsigned u = __float_as_uint(f);
  u = (u + 0x7FFFu + ((u >> 16) & 1u)) >> 16;
  return (unsigned short)u;
}
DEVI float bf2f(unsigned short h) { return __uint_as_float(((unsigned)h) << 16); }
DEVI float bf16r(float f) { return bf2f(f2bf(f)); }

// ---------- fast MXINT8 scale from block amax (amax normal, >0) ----------
// shared_exp = floor(log2(amax)) = exponent field - 127 (bit extract, no libm).
DEVI void mx_scales(float amax, float& scale, float& inv) {
  unsigned eb = __float_as_uint(amax) & 0x7f800000u;
  scale = __uint_as_float(eb - (6u << 23));          // 2^(e-6)
  inv   = __uint_as_float((260u << 23) - eb);        // 2^(6-e)
}

DEVI unsigned short quantv(float v, float scale, float inv) {
  float qv = rintf(v * inv);                          // RNE, matches jnp.round
  qv = fminf(fmaxf(qv, -128.f), 127.f);
  return f2bf(qv * scale);                            // exact in bf16
}

DEVI void quant8(const float* h, float amax, unsigned short* q) {
  if (amax > 0.f) {
    float scale, inv;
    mx_scales(amax, scale, inv);
#pragma unroll
    for (int k = 0; k < 8; ++k) q[k] = quantv(h[k], scale, inv);
  } else {
#pragma unroll
    for (int k = 0; k < 8; ++k) q[k] = 0;
  }
}

// ---------- async global->LDS 16B ----------
DEVI void gl2lds16(const void* g, void* l) {
  __builtin_amdgcn_global_load_lds(
      (__attribute__((address_space(1))) void*)const_cast<void*>(g),
      (__attribute__((address_space(3))) void*)l, 16, 0, 0);
}

DEVI uint4 pack8(const unsigned short* q) {
  uint4 o;
  o.x = (unsigned)q[0] | ((unsigned)q[1] << 16);
  o.y = (unsigned)q[2] | ((unsigned)q[3] << 16);
  o.z = (unsigned)q[4] | ((unsigned)q[5] << 16);
  o.w = (unsigned)q[6] | ((unsigned)q[7] << 16);
  return o;
}

// ---------- merged prep: W1 quant | W2 quant | LN+quant in ONE dispatch ----------
// blocks [0,8192): W1 ; [8192,16384): W2 ; [16384,20480): LN rows
__global__ __launch_bounds__(256) void prep_k(const float* __restrict__ W1,
                                              const float* __restrict__ W2,
                                              const float* __restrict__ X,
                                              const float* __restrict__ lw,
                                              const float* __restrict__ lb,
                                              unsigned short* __restrict__ qW1,
                                              unsigned short* __restrict__ qW2,
                                              unsigned short* __restrict__ a1) {
  __shared__ float red[4];
  const int bid = blockIdx.x;
  const int t = threadIdx.x;
  if (bid < 16384) {
    const float* src = (bid < 8192) ? W1 : W2;
    unsigned short* dst = (bid < 8192) ? qW1 : qW2;
    size_t idx = (size_t)(bid & 8191) * 256 + t;   // 8 elems/thread
    float4 v0 = ((const float4*)src)[idx * 2];
    float4 v1 = ((const float4*)src)[idx * 2 + 1];
    float h[8] = {v0.x, v0.y, v0.z, v0.w, v1.x, v1.y, v1.z, v1.w};
    float amax = 0.f;
#pragma unroll
    for (int k = 0; k < 8; ++k) amax = fmaxf(amax, fabsf(h[k]));
    amax = fmaxf(amax, __shfl_xor(amax, 1));   // 4 consecutive lanes = one 32-block
    amax = fmaxf(amax, __shfl_xor(amax, 2));
    unsigned short q[8];
    quant8(h, amax, q);
    ((uint4*)dst)[idx] = pack8(q);
  } else {
    const int H = 2048;
    const int row = bid - 16384;
    const int lane = t & 63, wave = t >> 6;
    const float* xr = X + (size_t)row * H;
    float4 v0 = ((const float4*)xr)[2 * t];
    float4 v1 = ((const float4*)xr)[2 * t + 1];
    float x[8] = {bf16r(v0.x), bf16r(v0.y), bf16r(v0.z), bf16r(v0.w),
                  bf16r(v1.x), bf16r(v1.y), bf16r(v1.z), bf16r(v1.w)};
    float s = 0.f;
#pragma unroll
    for (int k = 0; k < 8; ++k) s += x[k];
#pragma unroll
    for (int o = 32; o; o >>= 1) s += __shfl_xor(s, o);
    if (lane == 0) red[wave] = s;
    __syncthreads();
    float mu = (red[0] + red[1] + red[2] + red[3]) * (1.0f / H);
    __syncthreads();
    float v = 0.f;
#pragma unroll
    for (int k = 0; k < 8; ++k) { float d = x[k] - mu; v += d * d; }
#pragma unroll
    for (int o = 32; o; o >>= 1) v += __shfl_xor(v, o);
    if (lane == 0) red[wave] = v;
    __syncthreads();
    float var = (red[0] + red[1] + red[2] + red[3]) * (1.0f / H);
    float rstd = 1.0f / sqrtf(var + 1e-5f);
    float h[8];
    float amax = 0.f;
#pragma unroll
    for (int k = 0; k < 8; ++k) {
      int col = t * 8 + k;
      h[k] = bf16r((x[k] - mu) * rstd * lw[col] + lb[col]);
      amax = fmaxf(amax, fabsf(h[k]));
    }
    amax = fmaxf(amax, __shfl_xor(amax, 1));
    amax = fmaxf(amax, __shfl_xor(amax, 2));
    unsigned short q[8];
    quant8(h, amax, q);
    ((uint4*)(a1 + (size_t)row * H))[t] = pack8(q);
  }
}

// ---------- in-place MX quant of bf16 activations ----------
__global__ __launch_bounds__(256) void quant_bf16_ip(unsigned short* __restrict__ X) {
  size_t idx = (size_t)blockIdx.x * 256 + threadIdx.x;
  uint4 v = ((const uint4*)X)[idx];
  unsigned short u[8] = {(unsigned short)(v.x & 0xffff), (unsigned short)(v.x >> 16),
                         (unsigned short)(v.y & 0xffff), (unsigned short)(v.y >> 16),
                         (unsigned short)(v.z & 0xffff), (unsigned short)(v.z >> 16),
                         (unsigned short)(v.w & 0xffff), (unsigned short)(v.w >> 16)};
  float h[8];
#pragma unroll
  for (int k = 0; k < 8; ++k) h[k] = bf2f(u[k]);
  float amax = 0.f;
#pragma unroll
  for (int k = 0; k < 8; ++k) amax = fmaxf(amax, fabsf(h[k]));
  amax = fmaxf(amax, __shfl_xor(amax, 1));
  amax = fmaxf(amax, __shfl_xor(amax, 2));
  unsigned short q[8];
  quant8(h, amax, q);
  ((uint4*)X)[idx] = pack8(q);
}

// ---------- GEMM: C[m,n] = sum_k A[m,k]*B[n,k], A/B bf16, fp32 acc ----------
// 128x128 tile, BK=64, 4 waves, each wave 64x64 (4x4 of 16x16x32 MFMA).
// LDS XOR-swizzle: chunk c of row r at LDS chunk c^(r&7) (conflicts 5e7->0, R3).
// Epilogues kept LEAN: R4 showed a fused shfl-based quant costs +44us on the
// shared LDS pipe (128 ds_swizzle/thread) — quant stays a separate kernel.
// MODE 1: out = bf16(gelu(bf16(y + bias)))  -> ushort bf16 [M,N]
// MODE 2: out = bf16(bf16(resid) + bf16(y + bias)) -> float [M,N]
template <int MODE>
__global__ __launch_bounds__(256) void gemm_mx(const unsigned short* __restrict__ A,
                                               const unsigned short* __restrict__ B,
                                               int M, int N, int K,
                                               const float* __restrict__ bias,
                                               const float* __restrict__ resid,
                                               void* __restrict__ outp) {
  __shared__ unsigned short As[128 * 64];
  __shared__ unsigned short Bs[128 * 64];

  const int tid = threadIdx.x;
  const int lane = tid & 63;
  const int wave = tid >> 6;
  const int wr = (wave >> 1) * 64;   // wave row offset in tile
  const int wc = (wave & 1) * 64;    // wave col offset in tile
  const int lr = lane & 15;
  const int quad = lane >> 4;

  const int m0 = blockIdx.y * 128;
  const int n0 = blockIdx.x * 128;

  // staging: LDS unit n (fixed dest n*16 B) = row n>>3, LDS chunk n&7.
  // Source global chunk = (n&7) ^ (row&7)  [swizzle].
  size_t aoff[4], boff[4];
  int lbase[4];
#pragma unroll
  for (int j = 0; j < 4; ++j) {
    int n = j * 256 + tid;
    int r = n >> 3, c = (n & 7) ^ (r & 7);
    aoff[j] = (size_t)(m0 + r) * K + (size_t)c * 8;
    boff[j] = (size_t)(n0 + r) * K + (size_t)c * 8;
    lbase[j] = (j * 256 + (tid & ~63)) * 8;  // wave-uniform LDS base (ushort units)
  }

  f32x4 acc[4][4];
#pragma unroll
  for (int i = 0; i < 4; ++i)
#pragma unroll
    for (int j = 0; j < 4; ++j) acc[i][j] = (f32x4){0.f, 0.f, 0.f, 0.f};

  for (int k0 = 0; k0 < K; k0 += 64) {
#pragma unroll
    for (int j = 0; j < 4; ++j) gl2lds16(A + aoff[j] + k0, As + lbase[j]);
#pragma unroll
    for (int j = 0; j < 4; ++j) gl2lds16(B + boff[j] + k0, Bs + lbase[j]);
    __syncthreads();  // drains vmcnt -> LDS tiles visible
#pragma unroll
    for (int s = 0; s < 2; ++s) {
      bf16x8 af[4], bfr[4];
#pragma unroll
      for (int i = 0; i < 4; ++i) {
        int row = wr + i * 16 + lr;
        int ch = (s * 4 + quad) ^ (row & 7);
        af[i] = *(const bf16x8*)(As + row * 64 + ch * 8);
      }
#pragma unroll
      for (int j = 0; j < 4; ++j) {
        int row = wc + j * 16 + lr;
        int ch = (s * 4 + quad) ^ (row & 7);
        bfr[j] = *(const bf16x8*)(Bs + row * 64 + ch * 8);
      }
#pragma unroll
      for (int i = 0; i < 4; ++i)
#pragma unroll
        for (int j = 0; j < 4; ++j)
          acc[i][j] = __builtin_amdgcn_mfma_f32_16x16x32_bf16(af[i], bfr[j], acc[i][j], 0, 0, 0);
    }
    __syncthreads();  // all reads done before next stage overwrites
  }

  // epilogue: D mapping col = lane&15, row = quad*4 + reg   [m89-verified]
#pragma unroll
  for (int i = 0; i < 4; ++i) {
#pragma unroll
    for (int j = 0; j < 4; ++j) {
#pragma unroll
      for (int r = 0; r < 4; ++r) {
        int gm = m0 + wr + i * 16 + quad * 4 + r;
        int gn = n0 + wc + j * 16 + lr;
        float y = acc[i][j][r];
        if (MODE == 1) {
          float t = bf16r(y + bias[gn]);
          // tanh(u) = 1 - 2/(exp(2u)+1); exp via v_exp_f32. Saturates correctly.
          float u2 = 1.5957691216057308f * (t + 0.044715f * t * t * t);  // 2*c*(...)
          float E = __expf(u2);
          float th = 1.0f - 2.0f / (E + 1.0f);
          float g = 0.5f * t * (1.0f + th);
          ((unsigned short*)outp)[(size_t)gm * N + gn] = f2bf(g);
        } else {
          float h = bf16r(y + bias[gn]);
          float rr = bf16r(resid[(size_t)gm * N + gn]);
          ((float*)outp)[(size_t)gm * N + gn] = bf16r(rr + h);
        }
      }
    }
  }
  (void)M;
}

extern "C" void kernel_launch(void* const* d_in, const int* in_sizes, int n_in,
                              void* d_out, int out_size, void* d_ws, size_t ws_size,
                              hipStream_t stream) {
  const float* inputs = (const float*)d_in[0];  // [2,2048,2048]
  const float* ln_w   = (const float*)d_in[1];  // [2048]
  const float* ln_b   = (const float*)d_in[2];  // [2048]
  const float* W1     = (const float*)d_in[3];  // [8192,2048]
  const float* b1     = (const float*)d_in[4];  // [8192]
  const float* W2     = (const float*)d_in[5];  // [2048,8192]
  const float* b2     = (const float*)d_in[6];  // [2048]
  float* out = (float*)d_out;                   // [2,2048,2048] fp32 (bf16-valued)
  char* ws = (char*)d_ws;
  (void)in_sizes; (void)n_in; (void)out_size; (void)ws_size;

  // workspace layout (144 MiB total)
  unsigned short* qW1  = (unsigned short*)(ws);                      // 32 MiB
  unsigned short* qW2  = (unsigned short*)(ws + (size_t)33554432);   // 32 MiB
  unsigned short* a1   = (unsigned short*)(ws + (size_t)67108864);   // 16 MiB [4096,2048]
  unsigned short* act2 = (unsigned short*)(ws + (size_t)83886080);   // 64 MiB [4096,8192]

  const int M = 4096;

  // 1. merged prep: quantize W1+W2 and LN+quant the activations (one dispatch)
  prep_k<<<20480, 256, 0, stream>>>(W1, W2, inputs, ln_w, ln_b, qW1, qW2, a1);

  // 2. GEMM1 [4096,2048] x [8192,2048]^T + bias + gelu -> bf16 [4096,8192]
  gemm_mx<1><<<dim3(8192 / 128, M / 128), 256, 0, stream>>>(
      a1, qW1, M, 8192, 2048, b1, nullptr, (void*)act2);

  // 3. MX quant of activations in place
  quant_bf16_ip<<<16384, 256, 0, stream>>>(act2);

  // 4. GEMM2 [4096,8192] x [2048,8192]^T + bias + residual -> fp32 out
  gemm_mx<2><<<dim3(2048 / 128, M / 128), 256, 0, stream>>>(
      act2, qW2, M, 2048, 8192, b2, inputs, (void*)out);
}

// Round 6
// 503.600 us; speedup vs baseline: 1.0524x; 1.0399x over previous
//
#include <hip/hip_runtime.h>

#define DEVI __device__ __forceinline__

typedef __bf16 bf16x8 __attribute__((ext_vector_type(8)));
typedef float f32x4 __attribute__((ext_vector_type(4)));

// ---------- exact bf16 RNE helpers ----------
DEVI unsigned short f2bf(float f) {
  unsigned u = __float_as_uint(f);
  u = (u + 0x7FFFu + ((u >> 16) & 1u)) >> 16;
  return (unsigned short)u;
}
DEVI float bf2f(unsigned short h) { return __uint_as_float(((unsigned)h) << 16); }
DEVI float bf16r(float f) { return bf2f(f2bf(f)); }

// ---------- fast MXINT8 scale from block amax (amax normal, >0) ----------
// shared_exp = floor(log2(amax)) = exponent field - 127 (bit extract, no libm).
DEVI void mx_scales(float amax, float& scale, float& inv) {
  unsigned eb = __float_as_uint(amax) & 0x7f800000u;
  scale = __uint_as_float(eb - (6u << 23));          // 2^(e-6)
  inv   = __uint_as_float((260u << 23) - eb);        // 2^(6-e)
}

DEVI unsigned short quantv(float v, float scale, float inv) {
  float qv = rintf(v * inv);                          // RNE, matches jnp.round
  qv = fminf(fmaxf(qv, -128.f), 127.f);
  return f2bf(qv * scale);                            // exact in bf16
}

DEVI void quant8(const float* h, float amax, unsigned short* q) {
  if (amax > 0.f) {
    float scale, inv;
    mx_scales(amax, scale, inv);
#pragma unroll
    for (int k = 0; k < 8; ++k) q[k] = quantv(h[k], scale, inv);
  } else {
#pragma unroll
    for (int k = 0; k < 8; ++k) q[k] = 0;
  }
}

// ---------- 16-lane (DPP row) max reduction on the VALU pipe ----------
// row_ror:N keeps data within a 16-lane DPP row == one MFMA quad. Rotation
// butterfly {1,2,4,8} + fmax gives every lane the row max. No LDS traffic
// (R4's shfl_xor version hit the LDS pipe for ~+44us).
template <int N>
DEVI float qmax_step(float x) {
  int y = __builtin_amdgcn_update_dpp(0, __float_as_int(x), 0x120 | N, 0xF, 0xF, true);
  return fmaxf(x, __int_as_float(y));
}
DEVI float quad_row_max(float x) {
  x = qmax_step<1>(x);
  x = qmax_step<2>(x);
  x = qmax_step<4>(x);
  x = qmax_step<8>(x);
  return x;
}

// ---------- async global->LDS 16B ----------
DEVI void gl2lds16(const void* g, void* l) {
  __builtin_amdgcn_global_load_lds(
      (__attribute__((address_space(1))) void*)const_cast<void*>(g),
      (__attribute__((address_space(3))) void*)l, 16, 0, 0);
}

DEVI uint4 pack8(const unsigned short* q) {
  uint4 o;
  o.x = (unsigned)q[0] | ((unsigned)q[1] << 16);
  o.y = (unsigned)q[2] | ((unsigned)q[3] << 16);
  o.z = (unsigned)q[4] | ((unsigned)q[5] << 16);
  o.w = (unsigned)q[6] | ((unsigned)q[7] << 16);
  return o;
}

// ---------- merged prep: W1 quant | W2 quant | LN+quant in ONE dispatch ----------
// blocks [0,8192): W1 ; [8192,16384): W2 ; [16384,20480): LN rows
__global__ __launch_bounds__(256) void prep_k(const float* __restrict__ W1,
                                              const float* __restrict__ W2,
                                              const float* __restrict__ X,
                                              const float* __restrict__ lw,
                                              const float* __restrict__ lb,
                                              unsigned short* __restrict__ qW1,
                                              unsigned short* __restrict__ qW2,
                                              unsigned short* __restrict__ a1) {
  __shared__ float red[4];
  const int bid = blockIdx.x;
  const int t = threadIdx.x;
  if (bid < 16384) {
    const float* src = (bid < 8192) ? W1 : W2;
    unsigned short* dst = (bid < 8192) ? qW1 : qW2;
    size_t idx = (size_t)(bid & 8191) * 256 + t;   // 8 elems/thread
    float4 v0 = ((const float4*)src)[idx * 2];
    float4 v1 = ((const float4*)src)[idx * 2 + 1];
    float h[8] = {v0.x, v0.y, v0.z, v0.w, v1.x, v1.y, v1.z, v1.w};
    float amax = 0.f;
#pragma unroll
    for (int k = 0; k < 8; ++k) amax = fmaxf(amax, fabsf(h[k]));
    amax = fmaxf(amax, __shfl_xor(amax, 1));   // 4 consecutive lanes = one 32-block
    amax = fmaxf(amax, __shfl_xor(amax, 2));
    unsigned short q[8];
    quant8(h, amax, q);
    ((uint4*)dst)[idx] = pack8(q);
  } else {
    const int H = 2048;
    const int row = bid - 16384;
    const int lane = t & 63, wave = t >> 6;
    const float* xr = X + (size_t)row * H;
    float4 v0 = ((const float4*)xr)[2 * t];
    float4 v1 = ((const float4*)xr)[2 * t + 1];
    float x[8] = {bf16r(v0.x), bf16r(v0.y), bf16r(v0.z), bf16r(v0.w),
                  bf16r(v1.x), bf16r(v1.y), bf16r(v1.z), bf16r(v1.w)};
    float s = 0.f;
#pragma unroll
    for (int k = 0; k < 8; ++k) s += x[k];
#pragma unroll
    for (int o = 32; o; o >>= 1) s += __shfl_xor(s, o);
    if (lane == 0) red[wave] = s;
    __syncthreads();
    float mu = (red[0] + red[1] + red[2] + red[3]) * (1.0f / H);
    __syncthreads();
    float v = 0.f;
#pragma unroll
    for (int k = 0; k < 8; ++k) { float d = x[k] - mu; v += d * d; }
#pragma unroll
    for (int o = 32; o; o >>= 1) v += __shfl_xor(v, o);
    if (lane == 0) red[wave] = v;
    __syncthreads();
    float var = (red[0] + red[1] + red[2] + red[3]) * (1.0f / H);
    float rstd = 1.0f / sqrtf(var + 1e-5f);
    float h[8];
    float amax = 0.f;
#pragma unroll
    for (int k = 0; k < 8; ++k) {
      int col = t * 8 + k;
      h[k] = bf16r((x[k] - mu) * rstd * lw[col] + lb[col]);
      amax = fmaxf(amax, fabsf(h[k]));
    }
    amax = fmaxf(amax, __shfl_xor(amax, 1));
    amax = fmaxf(amax, __shfl_xor(amax, 2));
    unsigned short q[8];
    quant8(h, amax, q);
    ((uint4*)(a1 + (size_t)row * H))[t] = pack8(q);
  }
}

// ---------- GEMM: C[m,n] = sum_k A[m,k]*B[n,k], A/B bf16, fp32 acc ----------
// 128x128 tile, BK=64, 4 waves, each wave 64x64 (4x4 of 16x16x32 MFMA).
// LDS XOR-swizzle: chunk c of row r at LDS chunk c^(r&7) (conflicts 5e7->0, R3).
// MODE 1: h = bf16(gelu_tanh(bf16(y+bias)))  [tanhf: R3-proven, expf variant
//   cost +19us stall in R5] then FUSED MX-quant along N via DPP row max
//   (32-col block = one quad's 16 lanes x 2 j-tiles) -> quantized bf16 [M,N]
// MODE 2: out = bf16(bf16(resid) + bf16(y + bias)) -> float [M,N]
template <int MODE>
__global__ __launch_bounds__(256) void gemm_mx(const unsigned short* __restrict__ A,
                                               const unsigned short* __restrict__ B,
                                               int M, int N, int K,
                                               const float* __restrict__ bias,
                                               const float* __restrict__ resid,
                                               void* __restrict__ outp) {
  __shared__ unsigned short As[128 * 64];
  __shared__ unsigned short Bs[128 * 64];

  const int tid = threadIdx.x;
  const int lane = tid & 63;
  const int wave = tid >> 6;
  const int wr = (wave >> 1) * 64;   // wave row offset in tile
  const int wc = (wave & 1) * 64;    // wave col offset in tile
  const int lr = lane & 15;
  const int quad = lane >> 4;

  const int m0 = blockIdx.y * 128;
  const int n0 = blockIdx.x * 128;

  // staging: LDS unit n (fixed dest n*16 B) = row n>>3, LDS chunk n&7.
  // Source global chunk = (n&7) ^ (row&7)  [swizzle].
  size_t aoff[4], boff[4];
  int lbase[4];
#pragma unroll
  for (int j = 0; j < 4; ++j) {
    int n = j * 256 + tid;
    int r = n >> 3, c = (n & 7) ^ (r & 7);
    aoff[j] = (size_t)(m0 + r) * K + (size_t)c * 8;
    boff[j] = (size_t)(n0 + r) * K + (size_t)c * 8;
    lbase[j] = (j * 256 + (tid & ~63)) * 8;  // wave-uniform LDS base (ushort units)
  }

  f32x4 acc[4][4];
#pragma unroll
  for (int i = 0; i < 4; ++i)
#pragma unroll
    for (int j = 0; j < 4; ++j) acc[i][j] = (f32x4){0.f, 0.f, 0.f, 0.f};

  for (int k0 = 0; k0 < K; k0 += 64) {
#pragma unroll
    for (int j = 0; j < 4; ++j) gl2lds16(A + aoff[j] + k0, As + lbase[j]);
#pragma unroll
    for (int j = 0; j < 4; ++j) gl2lds16(B + boff[j] + k0, Bs + lbase[j]);
    __syncthreads();  // drains vmcnt -> LDS tiles visible
#pragma unroll
    for (int s = 0; s < 2; ++s) {
      bf16x8 af[4], bfr[4];
#pragma unroll
      for (int i = 0; i < 4; ++i) {
        int row = wr + i * 16 + lr;
        int ch = (s * 4 + quad) ^ (row & 7);
        af[i] = *(const bf16x8*)(As + row * 64 + ch * 8);
      }
#pragma unroll
      for (int j = 0; j < 4; ++j) {
        int row = wc + j * 16 + lr;
        int ch = (s * 4 + quad) ^ (row & 7);
        bfr[j] = *(const bf16x8*)(Bs + row * 64 + ch * 8);
      }
#pragma unroll
      for (int i = 0; i < 4; ++i)
#pragma unroll
        for (int j = 0; j < 4; ++j)
          acc[i][j] = __builtin_amdgcn_mfma_f32_16x16x32_bf16(af[i], bfr[j], acc[i][j], 0, 0, 0);
    }
    __syncthreads();  // all reads done before next stage overwrites
  }

  // epilogue: D mapping col = lane&15, row = quad*4 + reg   [m89-verified]
  if (MODE == 1) {
#pragma unroll
    for (int i = 0; i < 4; ++i) {
#pragma unroll
      for (int r = 0; r < 4; ++r) {
        const int gm = m0 + wr + i * 16 + quad * 4 + r;
        float g[4];
#pragma unroll
        for (int j = 0; j < 4; ++j) {
          float t = bf16r(acc[i][j][r] + bias[n0 + wc + j * 16 + lr]);
          float u = 0.7978845608028654f * (t + 0.044715f * t * t * t);
          g[j] = bf16r(0.5f * t * (1.0f + tanhf(u)));
        }
        // fused MX quant: 32-col block = {j0,j1} / {j2,j3} over this quad's lanes
        float a = quad_row_max(fmaxf(fabsf(g[0]), fabsf(g[1])));
        float b = quad_row_max(fmaxf(fabsf(g[2]), fabsf(g[3])));
        unsigned short q[4];
        if (a > 0.f) {
          float sc, iv; mx_scales(a, sc, iv);
          q[0] = quantv(g[0], sc, iv); q[1] = quantv(g[1], sc, iv);
        } else { q[0] = q[1] = 0; }
        if (b > 0.f) {
          float sc, iv; mx_scales(b, sc, iv);
          q[2] = quantv(g[2], sc, iv); q[3] = quantv(g[3], sc, iv);
        } else { q[2] = q[3] = 0; }
        unsigned short* orow = (unsigned short*)outp + (size_t)gm * N + n0 + wc + lr;
#pragma unroll
        for (int j = 0; j < 4; ++j) orow[j * 16] = q[j];
      }
    }
  } else {
#pragma unroll
    for (int i = 0; i < 4; ++i) {
#pragma unroll
      for (int j = 0; j < 4; ++j) {
#pragma unroll
        for (int r = 0; r < 4; ++r) {
          int gm = m0 + wr + i * 16 + quad * 4 + r;
          int gn = n0 + wc + j * 16 + lr;
          float h = bf16r(acc[i][j][r] + bias[gn]);
          float rr = bf16r(resid[(size_t)gm * N + gn]);
          ((float*)outp)[(size_t)gm * N + gn] = bf16r(rr + h);
        }
      }
    }
  }
  (void)M;
}

extern "C" void kernel_launch(void* const* d_in, const int* in_sizes, int n_in,
                              void* d_out, int out_size, void* d_ws, size_t ws_size,
                              hipStream_t stream) {
  const float* inputs = (const float*)d_in[0];  // [2,2048,2048]
  const float* ln_w   = (const float*)d_in[1];  // [2048]
  const float* ln_b   = (const float*)d_in[2];  // [2048]
  const float* W1     = (const float*)d_in[3];  // [8192,2048]
  const float* b1     = (const float*)d_in[4];  // [8192]
  const float* W2     = (const float*)d_in[5];  // [2048,8192]
  const float* b2     = (const float*)d_in[6];  // [2048]
  float* out = (float*)d_out;                   // [2,2048,2048] fp32 (bf16-valued)
  char* ws = (char*)d_ws;
  (void)in_sizes; (void)n_in; (void)out_size; (void)ws_size;

  // workspace layout (144 MiB total)
  unsigned short* qW1  = (unsigned short*)(ws);                      // 32 MiB
  unsigned short* qW2  = (unsigned short*)(ws + (size_t)33554432);   // 32 MiB
  unsigned short* a1   = (unsigned short*)(ws + (size_t)67108864);   // 16 MiB [4096,2048]
  unsigned short* act2 = (unsigned short*)(ws + (size_t)83886080);   // 64 MiB [4096,8192]

  const int M = 4096;

  // 1. merged prep: quantize W1+W2 and LN+quant the activations (one dispatch)
  prep_k<<<20480, 256, 0, stream>>>(W1, W2, inputs, ln_w, ln_b, qW1, qW2, a1);

  // 2. GEMM1 + bias + gelu + fused MX quant (DPP) -> quantized bf16 [4096,8192]
  gemm_mx<1><<<dim3(8192 / 128, M / 128), 256, 0, stream>>>(
      a1, qW1, M, 8192, 2048, b1, nullptr, (void*)act2);

  // 3. GEMM2 [4096,8192] x [2048,8192]^T + bias + residual -> fp32 out
  gemm_mx<2><<<dim3(2048 / 128, M / 128), 256, 0, stream>>>(
      act2, qW2, M, 2048, 8192, b2, inputs, (void*)out);
}